// Round 1
// baseline (65.576 us; speedup 1.0000x reference)
//
#include <hip/hip_runtime.h>

#define TILE_H 128
#define TILE_W 128
#define NUM_BINS 256
#define IMG_W 1024
#define IMG_H 1024

// One block (256 threads) per tile. 2048 tiles total.
__global__ __launch_bounds__(256) void clahe_kernel(const float* __restrict__ img,
                                                    float* __restrict__ out) {
    const int tile = blockIdx.x;          // 0..2047
    const int b  = tile >> 6;             // tile / 64
    const int ty = (tile >> 3) & 7;
    const int tx = tile & 7;

    const size_t base = ((size_t)b * IMG_H + (size_t)ty * TILE_H) * IMG_W + (size_t)tx * TILE_W;
    const float* __restrict__ src = img + base;
    float* __restrict__ dst = out + base;

    const int t = threadIdx.x;            // 0..255
    const int w = t >> 6;                 // wave id 0..3

    __shared__ int   hist[4][NUM_BINS];
    __shared__ float scan[NUM_BINS];
    __shared__ float cdf[NUM_BINS];
    __shared__ float exs[4];

    // zero sub-histograms
    hist[0][t] = 0; hist[1][t] = 0; hist[2][t] = 0; hist[3][t] = 0;
    __syncthreads();

    // ---- Pass 1: histogram. 16384 px = 4096 float4; thread t does f = t + i*256.
    // float4 index f -> row = f>>5 (32 float4 per 128-float row), col4 = f&31.
    #pragma unroll
    for (int i = 0; i < 16; ++i) {
        const int f   = t + (i << 8);
        const int row = f >> 5;
        const int c4  = f & 31;
        const float4 v = *reinterpret_cast<const float4*>(src + (size_t)row * IMG_W + (c4 << 2));
        int b0 = min(255, (int)(v.x * 256.0f));
        int b1 = min(255, (int)(v.y * 256.0f));
        int b2 = min(255, (int)(v.z * 256.0f));
        int b3 = min(255, (int)(v.w * 256.0f));
        atomicAdd(&hist[w][b0], 1);
        atomicAdd(&hist[w][b1], 1);
        atomicAdd(&hist[w][b2], 1);
        atomicAdd(&hist[w][b3], 1);
    }
    __syncthreads();

    // ---- Clip + redistribute. clip_count = 16384 * 2 / 256 = 128 exactly.
    const int h = hist[0][t] + hist[1][t] + hist[2][t] + hist[3][t];
    float ex = (float)max(h - 128, 0);

    // block-reduce excess: wave shuffle then LDS combine
    float e = ex;
    #pragma unroll
    for (int off = 32; off > 0; off >>= 1) e += __shfl_down(e, off);
    if ((t & 63) == 0) exs[w] = e;
    __syncthreads();
    const float excess = exs[0] + exs[1] + exs[2] + exs[3];

    const float hc = fminf((float)h, 128.0f) + excess * (1.0f / 256.0f);

    // ---- Inclusive scan over 256 bins (Hillis-Steele in LDS, 8 steps)
    scan[t] = hc;
    __syncthreads();
    #pragma unroll
    for (int off = 1; off < 256; off <<= 1) {
        const float v = (t >= off) ? scan[t - off] : 0.0f;
        __syncthreads();
        scan[t] += v;
        __syncthreads();
    }
    const float total = scan[NUM_BINS - 1];
    cdf[t] = scan[t] / total;
    __syncthreads();

    // ---- Pass 2: map (lookup idx uses *255, not *256) and write
    #pragma unroll
    for (int i = 0; i < 16; ++i) {
        const int f   = t + (i << 8);
        const int row = f >> 5;
        const int c4  = f & 31;
        const size_t off = (size_t)row * IMG_W + (c4 << 2);
        const float4 v = *reinterpret_cast<const float4*>(src + off);
        float4 o;
        o.x = cdf[min(255, (int)(v.x * 255.0f))];
        o.y = cdf[min(255, (int)(v.y * 255.0f))];
        o.z = cdf[min(255, (int)(v.z * 255.0f))];
        o.w = cdf[min(255, (int)(v.w * 255.0f))];
        *reinterpret_cast<float4*>(dst + off) = o;
    }
}

extern "C" void kernel_launch(void* const* d_in, const int* in_sizes, int n_in,
                              void* d_out, int out_size, void* d_ws, size_t ws_size,
                              hipStream_t stream) {
    const float* img = (const float*)d_in[0];
    float* out = (float*)d_out;
    // 32 batches * 8 * 8 tiles = 2048 blocks
    clahe_kernel<<<2048, 256, 0, stream>>>(img, out);
}